// Round 1
// baseline (1236.920 us; speedup 1.0000x reference)
//
#include <hip/hip_runtime.h>

#define SEQ   4096
#define HID   4096
#define EDIM  1024
#define NHEAD 4

typedef __attribute__((ext_vector_type(8))) short short8;
typedef __attribute__((ext_vector_type(4))) float f32x4;

typedef const __attribute__((address_space(1))) void* gas_ptr;
typedef __attribute__((address_space(3))) void* las_ptr;
#define GLD16(g, l) __builtin_amdgcn_global_load_lds((gas_ptr)(g), (las_ptr)(l), 16, 0, 0)

__device__ __forceinline__ unsigned short f2bf(float f) {
  union { float f; unsigned u; } v; v.f = f;
  unsigned r = v.u + 0x7fffu + ((v.u >> 16) & 1u);  // RNE
  return (unsigned short)(r >> 16);
}
__device__ __forceinline__ float bf2f(unsigned short u) {
  union { unsigned u; float f; } v; v.u = ((unsigned)u) << 16;
  return v.f;
}

// ---------------- h: f32 -> bf16 ----------------
__global__ __launch_bounds__(256) void hconv_kernel(const float* __restrict__ in,
                                                    unsigned short* __restrict__ out) {
  size_t i = ((size_t)blockIdx.x * 256 + threadIdx.x) * 8;
  const float4 a = *(const float4*)(in + i);
  const float4 b = *(const float4*)(in + i + 4);
  short8 o;
  o[0] = (short)f2bf(a.x); o[1] = (short)f2bf(a.y);
  o[2] = (short)f2bf(a.z); o[3] = (short)f2bf(a.w);
  o[4] = (short)f2bf(b.x); o[5] = (short)f2bf(b.y);
  o[6] = (short)f2bf(b.z); o[7] = (short)f2bf(b.w);
  *(short8*)(out + i) = o;
}

// ---------------- W [mat][head][D][E] f32 -> Wt [mat*4+head][E][D] bf16 ----------------
__global__ __launch_bounds__(256) void wconv_kernel(const float* __restrict__ Wq,
                                                    const float* __restrict__ Wk,
                                                    const float* __restrict__ Wv,
                                                    unsigned short* __restrict__ wt) {
  const int mh = blockIdx.y;               // 0..11
  const int mat = mh >> 2, head = mh & 3;
  const float* W = (mat == 0 ? Wq : (mat == 1 ? Wk : Wv)) + (size_t)head * HID * EDIM; // [D][E]
  unsigned short* out = wt + (size_t)mh * EDIM * HID;                                  // [E][D]
  const int tile = blockIdx.x;             // (D/64)*(E/64) = 64*16
  const int td = tile >> 4;                // d-tile 0..63
  const int te = tile & 15;                // e-tile 0..15
  __shared__ float lds[64][65];
  const int tid = threadIdx.x;
  const int r = tid >> 4, c4 = (tid & 15) * 4;
#pragma unroll
  for (int it = 0; it < 4; ++it) {
    int dr = r + 16 * it;
    const float4 v = *(const float4*)&W[(size_t)(td * 64 + dr) * EDIM + te * 64 + c4];
    lds[dr][c4 + 0] = v.x; lds[dr][c4 + 1] = v.y;
    lds[dr][c4 + 2] = v.z; lds[dr][c4 + 3] = v.w;
  }
  __syncthreads();
#pragma unroll
  for (int it = 0; it < 4; ++it) {
    int er = r + 16 * it;
    ushort4 o;
    o.x = f2bf(lds[c4 + 0][er]); o.y = f2bf(lds[c4 + 1][er]);
    o.z = f2bf(lds[c4 + 2][er]); o.w = f2bf(lds[c4 + 3][er]);
    *(ushort4*)&out[(size_t)(te * 64 + er) * HID + td * 64 + c4] = o;
  }
}

// ---------------- 128x128 bf16 MFMA GEMM, C = A * Bt^T ----------------
// A [M][K] row-major bf16, Bt [N][K] row-major bf16. BK=32, 4 waves, 64x64/wave.
// MODE 0: bf16 out [row][col], +bias[col]
// MODE 1: bf16 out [col][row], +bias[col]   (transposed write, for V^T)
// MODE 2: bf16 out [row][col], *scale       (scores)
// MODE 3: f32  out [row][col]               (final output)
template <int MODE>
__global__ __launch_bounds__(256) void gemm128_kernel(
    const unsigned short* __restrict__ Aall, const unsigned short* __restrict__ Ball,
    long long aBatch, long long bBatch, int M, int N, int K,
    const float* __restrict__ biasAll, long long biasBatch,
    void* __restrict__ outAll, long long outBatch, int ldOut, float scale) {
  __shared__ __align__(16) unsigned short Al[128 * 32];
  __shared__ __align__(16) unsigned short Bl[128 * 32];
  const int z = blockIdx.z;
  const unsigned short* A = Aall + (size_t)z * aBatch;
  const unsigned short* B = Ball + (size_t)z * bBatch;
  const int bm = blockIdx.y * 128, bn = blockIdx.x * 128;
  const int tid = threadIdx.x;
  const int lane = tid & 63, wid = tid >> 6;
  const int wr = wid >> 1, wc = wid & 1;
  const int li = lane & 15, lg = lane >> 4;

  f32x4 acc[4][4];
#pragma unroll
  for (int m = 0; m < 4; ++m)
#pragma unroll
    for (int n = 0; n < 4; ++n) acc[m][n] = (f32x4){0.f, 0.f, 0.f, 0.f};

  const int srow = tid >> 2;
  const int scol = (tid & 3) * 8;
  const unsigned short* aG0 = A + (size_t)(bm + srow) * K + scol;
  const unsigned short* aG1 = aG0 + (size_t)64 * K;
  const unsigned short* bG0 = B + (size_t)(bn + srow) * K + scol;
  const unsigned short* bG1 = bG0 + (size_t)64 * K;
  unsigned short* aL = Al + tid * 8;  // byte offset tid*16 (HW: wave base + lane*16)
  unsigned short* bL = Bl + tid * 8;

  for (int k0 = 0; k0 < K; k0 += 32) {
    GLD16(aG0 + k0, aL);
    GLD16(aG1 + k0, aL + 2048);
    GLD16(bG0 + k0, bL);
    GLD16(bG1 + k0, bL + 2048);
    __syncthreads();
    short8 af[4], bfr[4];
#pragma unroll
    for (int m = 0; m < 4; ++m)
      af[m] = *(const short8*)&Al[(wr * 64 + m * 16 + li) * 32 + lg * 8];
#pragma unroll
    for (int n = 0; n < 4; ++n)
      bfr[n] = *(const short8*)&Bl[(wc * 64 + n * 16 + li) * 32 + lg * 8];
#pragma unroll
    for (int m = 0; m < 4; ++m)
#pragma unroll
      for (int n = 0; n < 4; ++n)
        acc[m][n] = __builtin_amdgcn_mfma_f32_16x16x32_bf16(af[m], bfr[n], acc[m][n], 0, 0, 0);
    __syncthreads();
  }

  const float* bias = (MODE == 0 || MODE == 1) ? biasAll + (size_t)z * biasBatch : nullptr;
#pragma unroll
  for (int m = 0; m < 4; ++m)
#pragma unroll
    for (int n = 0; n < 4; ++n)
#pragma unroll
      for (int r = 0; r < 4; ++r) {
        const int grow = bm + wr * 64 + m * 16 + lg * 4 + r;
        const int gcol = bn + wc * 64 + n * 16 + li;
        float val = acc[m][n][r];
        if (MODE == 0 || MODE == 1) val += bias[gcol];
        if (MODE == 2) val *= scale;
        if (MODE == 0 || MODE == 2) {
          unsigned short* o = (unsigned short*)outAll + (size_t)z * outBatch;
          o[(size_t)grow * ldOut + gcol] = f2bf(val);
        } else if (MODE == 1) {
          unsigned short* o = (unsigned short*)outAll + (size_t)z * outBatch;
          o[(size_t)gcol * ldOut + grow] = f2bf(val);
        } else {
          float* o = (float*)outAll + (size_t)z * outBatch;
          o[(size_t)grow * ldOut + gcol] = val;
        }
      }
}

// ---------------- row softmax, in place on bf16 [nrows][SEQ] ----------------
__global__ __launch_bounds__(256) void softmax_kernel(unsigned short* __restrict__ Sb) {
  const size_t row = blockIdx.x;
  unsigned short* p = Sb + row * (size_t)SEQ;
  const int tid = threadIdx.x;
  const int lane = tid & 63, wid = tid >> 6;
  float v[16];
  const short8 u0 = *(const short8*)&p[tid * 16];
  const short8 u1 = *(const short8*)&p[tid * 16 + 8];
#pragma unroll
  for (int j = 0; j < 8; ++j) v[j] = bf2f((unsigned short)u0[j]);
#pragma unroll
  for (int j = 0; j < 8; ++j) v[8 + j] = bf2f((unsigned short)u1[j]);
  float mx = v[0];
#pragma unroll
  for (int j = 1; j < 16; ++j) mx = fmaxf(mx, v[j]);
#pragma unroll
  for (int off = 32; off; off >>= 1) mx = fmaxf(mx, __shfl_xor(mx, off));
  __shared__ float red[8];
  if (lane == 0) red[wid] = mx;
  __syncthreads();
  mx = fmaxf(fmaxf(red[0], red[1]), fmaxf(red[2], red[3]));
  float s = 0.f;
#pragma unroll
  for (int j = 0; j < 16; ++j) { v[j] = __expf(v[j] - mx); s += v[j]; }
#pragma unroll
  for (int off = 32; off; off >>= 1) s += __shfl_xor(s, off);
  if (lane == 0) red[4 + wid] = s;
  __syncthreads();
  s = (red[4] + red[5]) + (red[6] + red[7]);
  const float inv = 1.0f / s;
  short8 o0, o1;
#pragma unroll
  for (int j = 0; j < 8; ++j) o0[j] = (short)f2bf(v[j] * inv);
#pragma unroll
  for (int j = 0; j < 8; ++j) o1[j] = (short)f2bf(v[8 + j] * inv);
  *(short8*)&p[tid * 16] = o0;
  *(short8*)&p[tid * 16 + 8] = o1;
}

extern "C" void kernel_launch(void* const* d_in, const int* in_sizes, int n_in,
                              void* d_out, int out_size, void* d_ws, size_t ws_size,
                              hipStream_t stream) {
  const float* h  = (const float*)d_in[0];
  const float* Wq = (const float*)d_in[1];
  const float* bq = (const float*)d_in[2];
  const float* Wk = (const float*)d_in[3];
  const float* bk = (const float*)d_in[4];
  const float* Wv = (const float*)d_in[5];
  const float* bv = (const float*)d_in[6];
  float* out = (float*)d_out;
  char* ws = (char*)d_ws;

  // ws layout (224 MB):
  //  [0,32MB)    h_bf16 [S][HID]          -- dead after projections
  //  [32,128MB)  Wt bf16 [12][E][HID]     -- dead after projections
  //  [0,128MB)   Sb bf16 [H][S][S]        -- scores/probs (reuses the two above)
  //  [128,160)   Qb bf16 [H][S][E]
  //  [160,192)   Kb bf16 [H][S][E]
  //  [192,224)   Vt bf16 [H][E][S]
  unsigned short* hB = (unsigned short*)ws;
  unsigned short* wt = (unsigned short*)(ws + (32ull << 20));
  unsigned short* Sb = (unsigned short*)ws;
  unsigned short* Qb = (unsigned short*)(ws + (128ull << 20));
  unsigned short* Kb = (unsigned short*)(ws + (160ull << 20));
  unsigned short* Vt = (unsigned short*)(ws + (192ull << 20));

  const long long WED = (long long)EDIM * HID;   // per-(mat,head) Wt elems
  const long long QKB = (long long)SEQ * EDIM;   // per-head Q/K elems
  const long long SSB = (long long)SEQ * SEQ;    // per-head score elems

  hconv_kernel<<<dim3((SEQ * (size_t)HID) / (256 * 8)), 256, 0, stream>>>(h, hB);
  wconv_kernel<<<dim3((HID / 64) * (EDIM / 64), 12), 256, 0, stream>>>(Wq, Wk, Wv, wt);

  // Projections: M=S, N=E, K=HID  (grid: N/128 x M/128 x heads)
  gemm128_kernel<0><<<dim3(EDIM / 128, SEQ / 128, NHEAD), 256, 0, stream>>>(
      hB, wt + 0 * WED, 0, WED, SEQ, EDIM, HID, bq, EDIM, Qb, QKB, EDIM, 1.f);
  gemm128_kernel<0><<<dim3(EDIM / 128, SEQ / 128, NHEAD), 256, 0, stream>>>(
      hB, wt + 4 * WED, 0, WED, SEQ, EDIM, HID, bk, EDIM, Kb, QKB, EDIM, 1.f);
  gemm128_kernel<1><<<dim3(EDIM / 128, SEQ / 128, NHEAD), 256, 0, stream>>>(
      hB, wt + 8 * WED, 0, WED, SEQ, EDIM, HID, bv, EDIM, Vt, QKB, SEQ, 1.f);

  // Scores: S = Q K^T / 32   (M=N=S, K=E)
  gemm128_kernel<2><<<dim3(SEQ / 128, SEQ / 128, NHEAD), 256, 0, stream>>>(
      Qb, Kb, QKB, QKB, SEQ, SEQ, EDIM, nullptr, 0, Sb, SSB, SEQ, 0.03125f);

  // Softmax over rows, in place
  softmax_kernel<<<dim3(NHEAD * SEQ), 256, 0, stream>>>(Sb);

  // Out: O = P V  (M=S, N=E, K=S), written to out[s][head*E + e] as f32
  gemm128_kernel<3><<<dim3(EDIM / 128, SEQ / 128, NHEAD), 256, 0, stream>>>(
      Sb, Vt, SSB, QKB, SEQ, EDIM, SEQ, nullptr, 0, out, (long long)EDIM, NHEAD * EDIM, 1.f);
}

// Round 2
// 768.984 us; speedup vs baseline: 1.6085x; 1.6085x over previous
//
#include <hip/hip_runtime.h>

#define SEQ   4096
#define HID   4096
#define EDIM  1024
#define NHEAD 4

typedef __attribute__((ext_vector_type(8))) short short8;
typedef __attribute__((ext_vector_type(4))) float f32x4;

typedef const __attribute__((address_space(1))) void* gas_ptr;
typedef __attribute__((address_space(3))) void* las_ptr;
#define GLD16(g, l) __builtin_amdgcn_global_load_lds((gas_ptr)(g), (las_ptr)(l), 16, 0, 0)

#define BARRIER() __builtin_amdgcn_s_barrier()
#define SCHED0()  __builtin_amdgcn_sched_barrier(0)

__device__ __forceinline__ unsigned short f2bf(float f) {
  union { float f; unsigned u; } v; v.f = f;
  unsigned r = v.u + 0x7fffu + ((v.u >> 16) & 1u);  // RNE
  return (unsigned short)(r >> 16);
}
__device__ __forceinline__ float bf2f(unsigned short u) {
  union { unsigned u; float f; } v; v.u = ((unsigned)u) << 16;
  return v.f;
}

// ---------------- h: f32 -> bf16 ----------------
__global__ __launch_bounds__(256) void hconv_kernel(const float* __restrict__ in,
                                                    unsigned short* __restrict__ out) {
  size_t i = ((size_t)blockIdx.x * 256 + threadIdx.x) * 8;
  const float4 a = *(const float4*)(in + i);
  const float4 b = *(const float4*)(in + i + 4);
  short8 o;
  o[0] = (short)f2bf(a.x); o[1] = (short)f2bf(a.y);
  o[2] = (short)f2bf(a.z); o[3] = (short)f2bf(a.w);
  o[4] = (short)f2bf(b.x); o[5] = (short)f2bf(b.y);
  o[6] = (short)f2bf(b.z); o[7] = (short)f2bf(b.w);
  *(short8*)(out + i) = o;
}

// ---------------- W [mat][head][D][E] f32 -> Wt [mat*4+head][E][D] bf16 ----------------
__global__ __launch_bounds__(256) void wconv_kernel(const float* __restrict__ Wq,
                                                    const float* __restrict__ Wk,
                                                    const float* __restrict__ Wv,
                                                    unsigned short* __restrict__ wt) {
  const int mh = blockIdx.y;               // 0..11
  const int mat = mh >> 2, head = mh & 3;
  const float* W = (mat == 0 ? Wq : (mat == 1 ? Wk : Wv)) + (size_t)head * HID * EDIM; // [D][E]
  unsigned short* out = wt + (size_t)mh * EDIM * HID;                                  // [E][D]
  const int tile = blockIdx.x;             // (D/64)*(E/64) = 64*16
  const int td = tile >> 4;                // d-tile 0..63
  const int te = tile & 15;                // e-tile 0..15
  __shared__ float lds[64][65];
  const int tid = threadIdx.x;
  const int r = tid >> 4, c4 = (tid & 15) * 4;
#pragma unroll
  for (int it = 0; it < 4; ++it) {
    int dr = r + 16 * it;
    const float4 v = *(const float4*)&W[(size_t)(td * 64 + dr) * EDIM + te * 64 + c4];
    lds[dr][c4 + 0] = v.x; lds[dr][c4 + 1] = v.y;
    lds[dr][c4 + 2] = v.z; lds[dr][c4 + 3] = v.w;
  }
  __syncthreads();
#pragma unroll
  for (int it = 0; it < 4; ++it) {
    int er = r + 16 * it;
    ushort4 o;
    o.x = f2bf(lds[c4 + 0][er]); o.y = f2bf(lds[c4 + 1][er]);
    o.z = f2bf(lds[c4 + 2][er]); o.w = f2bf(lds[c4 + 3][er]);
    *(ushort4*)&out[(size_t)(te * 64 + er) * HID + td * 64 + c4] = o;
  }
}

// ---------------- 256x256 deep-pipelined bf16 MFMA GEMM, C = A * Bt^T ----------------
// A [M][K] row-major bf16, Bt [N][K] row-major bf16. BK=32, 8 waves (2x4), 128x64/wave.
// 4-deep LDS ring of K-tiles (32KB each = A 16KB + B 16KB), staged 3 tiles ahead with
// global_load_lds(16B); counted vmcnt(8) once per K-tile; raw s_barrier; XOR-swizzled
// LDS reads with inverse-swizzled staging source (slot ^= (row>>1)&3, rows are 64B).
// MODE 0: bf16 out [row][col], +bias[col]
// MODE 1: bf16 out [col][row], +bias[col]   (transposed write, for V^T)
// MODE 2: bf16 out [row][col], *scale       (scores)
// MODE 3: f32  out [row][col]               (final output)
template <int MODE>
__global__ __launch_bounds__(512, 2) void gemm256_kernel(
    const unsigned short* __restrict__ Aall, const unsigned short* __restrict__ Ball,
    long long aBatch, long long bBatch, int K,
    const float* __restrict__ biasAll, long long biasBatch,
    void* __restrict__ outAll, long long outBatch, int ldOut, float scale,
    int gx, int gxy) {
  extern __shared__ char smem[];

  // XCD-aware bijective block swizzle (all grids have nwg % 8 == 0)
  const int nwg = (int)gridDim.x;
  const int lin = (int)blockIdx.x;
  int wg = (lin & 7) * (nwg >> 3) + (lin >> 3);
  const int z = wg / gxy; wg -= z * gxy;
  const int by = wg / gx;
  const int bx = wg - by * gx;
  const int bm = by * 256, bn = bx * 256;

  const unsigned short* A = Aall + (size_t)z * aBatch;
  const unsigned short* B = Ball + (size_t)z * bBatch;

  const int tid = threadIdx.x;           // 0..511
  const int lane = tid & 63, wid = tid >> 6;
  const int wr = wid >> 2, wc = wid & 3; // wave -> (2 x 4) output grid
  const int li = lane & 15, lg = lane >> 4;

  // ---- staging: per thread 2 A-chunks + 2 B-chunks (16B each) per K-tile.
  // chunk c covers LDS row c>>2, 16B-slot c&3; source k-slot is XOR-permuted so that
  // the swizzled read below lands on the right fragment (both-sides involution).
  const int r0 = tid >> 2, s0 = tid & 3;
  const int kx = (s0 ^ ((r0 >> 1) & 3)) * 8;   // (r0+128)>>1 has same &3 -> same kx
  const unsigned short* aS0 = A + (size_t)(bm + r0) * K + kx;
  const unsigned short* aS1 = A + (size_t)(bm + r0 + 128) * K + kx;
  const unsigned short* bS0 = B + (size_t)(bn + r0) * K + kx;
  const unsigned short* bS1 = B + (size_t)(bn + r0 + 128) * K + kx;
  char* dA0 = smem + tid * 16;
  char* dA1 = smem + tid * 16 + 8192;
  char* dB0 = smem + 16384 + tid * 16;
  char* dB1 = smem + 16384 + tid * 16 + 8192;

  // ---- swizzled ds_read bases (within a ring slot)
  const int swz = (li >> 1) & 3;
  const int aOff = (wr * 128 + li) * 64 + ((lg ^ swz) * 16);          // + m*1024
  const int bOff = 16384 + (wc * 64 + li) * 64 + ((lg ^ swz) * 16);   // + n*1024

  f32x4 acc[8][4];
#pragma unroll
  for (int m = 0; m < 8; ++m)
#pragma unroll
    for (int n = 0; n < 4; ++n) acc[m][n] = (f32x4){0.f, 0.f, 0.f, 0.f};

  const int NT = K >> 5;   // K-tiles of 32

  // ---- prologue: stage tiles 0..2 (12 loads/thread), wait tile 0 landed
  for (int t = 0; t < 3; ++t) {
    const int rg = (t & 3) * 32768;
    GLD16(aS0 + (size_t)t * 32, dA0 + rg);
    GLD16(aS1 + (size_t)t * 32, dA1 + rg);
    GLD16(bS0 + (size_t)t * 32, dB0 + rg);
    GLD16(bS1 + (size_t)t * 32, dB1 + rg);
  }
  asm volatile("s_waitcnt vmcnt(8)" ::: "memory");
  BARRIER();
  SCHED0();

  for (int t = 0; t < NT; ++t) {
    const char* base = smem + (t & 3) * 32768;
    short8 av[8], bv[4];
    // ================= phase 0: m 0..3 x n 0..3 =================
#pragma unroll
    for (int m = 0; m < 4; ++m) av[m] = *(const short8*)(base + aOff + m * 1024);
#pragma unroll
    for (int n = 0; n < 4; ++n) bv[n] = *(const short8*)(base + bOff + n * 1024);
    if (t + 3 < NT) {
      const int rg = ((t + 3) & 3) * 32768;
      GLD16(aS0 + (size_t)(t + 3) * 32, dA0 + rg);
      GLD16(aS1 + (size_t)(t + 3) * 32, dA1 + rg);
    }
    SCHED0();
    BARRIER();
    asm volatile("s_waitcnt lgkmcnt(0)" ::: "memory");
    SCHED0();
    __builtin_amdgcn_s_setprio(1);
#pragma unroll
    for (int m = 0; m < 4; ++m)
#pragma unroll
      for (int n = 0; n < 4; ++n)
        acc[m][n] = __builtin_amdgcn_mfma_f32_16x16x32_bf16(av[m], bv[n], acc[m][n], 0, 0, 0);
    __builtin_amdgcn_s_setprio(0);
    SCHED0();
    BARRIER();
    SCHED0();
    // ================= phase 1: m 4..7 x n 0..3 =================
#pragma unroll
    for (int m = 4; m < 8; ++m) av[m] = *(const short8*)(base + aOff + m * 1024);
    if (t + 3 < NT) {
      const int rg = ((t + 3) & 3) * 32768;
      GLD16(bS0 + (size_t)(t + 3) * 32, dB0 + rg);
      GLD16(bS1 + (size_t)(t + 3) * 32, dB1 + rg);
    }
    // counted vmcnt once per K-tile: keep 2 tiles (8 loads) in flight
    if (t < NT - 3) {
      asm volatile("s_waitcnt vmcnt(8)" ::: "memory");
    } else if (t == NT - 3) {
      asm volatile("s_waitcnt vmcnt(4)" ::: "memory");
    } else if (t == NT - 2) {
      asm volatile("s_waitcnt vmcnt(0)" ::: "memory");
    }
    SCHED0();
    BARRIER();
    asm volatile("s_waitcnt lgkmcnt(0)" ::: "memory");
    SCHED0();
    __builtin_amdgcn_s_setprio(1);
#pragma unroll
    for (int m = 4; m < 8; ++m)
#pragma unroll
      for (int n = 0; n < 4; ++n)
        acc[m][n] = __builtin_amdgcn_mfma_f32_16x16x32_bf16(av[m], bv[n], acc[m][n], 0, 0, 0);
    __builtin_amdgcn_s_setprio(0);
    SCHED0();
    BARRIER();
    SCHED0();
  }

  // ---- epilogue
  float bvv[4];
  if (MODE == 0 || MODE == 1) {
    const float* bias = biasAll + (size_t)z * biasBatch;
#pragma unroll
    for (int n = 0; n < 4; ++n) bvv[n] = bias[bn + wc * 64 + n * 16 + li];
  }
#pragma unroll
  for (int m = 0; m < 8; ++m)
#pragma unroll
    for (int n = 0; n < 4; ++n)
#pragma unroll
      for (int r = 0; r < 4; ++r) {
        const int grow = bm + wr * 128 + m * 16 + lg * 4 + r;
        const int gcol = bn + wc * 64 + n * 16 + li;
        float val = acc[m][n][r];
        if (MODE == 0 || MODE == 1) val += bvv[n];
        if (MODE == 2) val *= scale;
        if (MODE == 0 || MODE == 2) {
          unsigned short* o = (unsigned short*)outAll + (size_t)z * outBatch;
          o[(size_t)grow * ldOut + gcol] = f2bf(val);
        } else if (MODE == 1) {
          unsigned short* o = (unsigned short*)outAll + (size_t)z * outBatch;
          o[(size_t)gcol * ldOut + grow] = f2bf(val);
        } else {
          float* o = (float*)outAll + (size_t)z * outBatch;
          o[(size_t)grow * ldOut + gcol] = val;
        }
      }
}

// ---------------- row softmax, in place on bf16 [nrows][SEQ] ----------------
__global__ __launch_bounds__(256) void softmax_kernel(unsigned short* __restrict__ Sb) {
  const size_t row = blockIdx.x;
  unsigned short* p = Sb + row * (size_t)SEQ;
  const int tid = threadIdx.x;
  const int lane = tid & 63, wid = tid >> 6;
  float v[16];
  const short8 u0 = *(const short8*)&p[tid * 16];
  const short8 u1 = *(const short8*)&p[tid * 16 + 8];
#pragma unroll
  for (int j = 0; j < 8; ++j) v[j] = bf2f((unsigned short)u0[j]);
#pragma unroll
  for (int j = 0; j < 8; ++j) v[8 + j] = bf2f((unsigned short)u1[j]);
  float mx = v[0];
#pragma unroll
  for (int j = 1; j < 16; ++j) mx = fmaxf(mx, v[j]);
#pragma unroll
  for (int off = 32; off; off >>= 1) mx = fmaxf(mx, __shfl_xor(mx, off));
  __shared__ float red[8];
  if (lane == 0) red[wid] = mx;
  __syncthreads();
  mx = fmaxf(fmaxf(red[0], red[1]), fmaxf(red[2], red[3]));
  float s = 0.f;
#pragma unroll
  for (int j = 0; j < 16; ++j) { v[j] = __expf(v[j] - mx); s += v[j]; }
#pragma unroll
  for (int off = 32; off; off >>= 1) s += __shfl_xor(s, off);
  if (lane == 0) red[4 + wid] = s;
  __syncthreads();
  s = (red[4] + red[5]) + (red[6] + red[7]);
  const float inv = 1.0f / s;
  short8 o0, o1;
#pragma unroll
  for (int j = 0; j < 8; ++j) o0[j] = (short)f2bf(v[j] * inv);
#pragma unroll
  for (int j = 0; j < 8; ++j) o1[j] = (short)f2bf(v[8 + j] * inv);
  *(short8*)&p[tid * 16] = o0;
  *(short8*)&p[tid * 16 + 8] = o1;
}

extern "C" void kernel_launch(void* const* d_in, const int* in_sizes, int n_in,
                              void* d_out, int out_size, void* d_ws, size_t ws_size,
                              hipStream_t stream) {
  const float* h  = (const float*)d_in[0];
  const float* Wq = (const float*)d_in[1];
  const float* bq = (const float*)d_in[2];
  const float* Wk = (const float*)d_in[3];
  const float* bk = (const float*)d_in[4];
  const float* Wv = (const float*)d_in[5];
  const float* bv = (const float*)d_in[6];
  float* out = (float*)d_out;
  char* ws = (char*)d_ws;

  // allow 128KB dynamic LDS for the GEMM kernels (idempotent, not a stream op)
  (void)hipFuncSetAttribute((const void*)&gemm256_kernel<0>,
                            hipFuncAttributeMaxDynamicSharedMemorySize, 131072);
  (void)hipFuncSetAttribute((const void*)&gemm256_kernel<1>,
                            hipFuncAttributeMaxDynamicSharedMemorySize, 131072);
  (void)hipFuncSetAttribute((const void*)&gemm256_kernel<2>,
                            hipFuncAttributeMaxDynamicSharedMemorySize, 131072);
  (void)hipFuncSetAttribute((const void*)&gemm256_kernel<3>,
                            hipFuncAttributeMaxDynamicSharedMemorySize, 131072);

  // ws layout (224 MB):
  //  [0,32MB)    h_bf16 [S][HID]          -- dead after projections
  //  [32,128MB)  Wt bf16 [12][E][HID]     -- dead after projections
  //  [0,128MB)   Sb bf16 [H][S][S]        -- scores/probs (reuses the two above)
  //  [128,160)   Qb bf16 [H][S][E]
  //  [160,192)   Kb bf16 [H][S][E]
  //  [192,224)   Vt bf16 [H][E][S]
  unsigned short* hB = (unsigned short*)ws;
  unsigned short* wt = (unsigned short*)(ws + (32ull << 20));
  unsigned short* Sb = (unsigned short*)ws;
  unsigned short* Qb = (unsigned short*)(ws + (128ull << 20));
  unsigned short* Kb = (unsigned short*)(ws + (160ull << 20));
  unsigned short* Vt = (unsigned short*)(ws + (192ull << 20));

  const long long WED = (long long)EDIM * HID;   // per-(mat,head) Wt elems
  const long long QKB = (long long)SEQ * EDIM;   // per-head Q/K elems
  const long long SSB = (long long)SEQ * SEQ;    // per-head score elems

  hconv_kernel<<<dim3((SEQ * (size_t)HID) / (256 * 8)), 256, 0, stream>>>(h, hB);
  wconv_kernel<<<dim3((HID / 64) * (EDIM / 64), 12), 256, 0, stream>>>(Wq, Wk, Wv, wt);

  // Projections: M=S=4096, N=E=1024, K=HID  -> grid (4 x 16 x 4) = 256 blocks, 1-D
  gemm256_kernel<0><<<dim3(4 * 16 * 4), 512, 131072, stream>>>(
      hB, wt + 0 * WED, 0, WED, HID, bq, EDIM, Qb, QKB, EDIM, 1.f, 4, 64);
  gemm256_kernel<0><<<dim3(4 * 16 * 4), 512, 131072, stream>>>(
      hB, wt + 4 * WED, 0, WED, HID, bk, EDIM, Kb, QKB, EDIM, 1.f, 4, 64);
  gemm256_kernel<1><<<dim3(4 * 16 * 4), 512, 131072, stream>>>(
      hB, wt + 8 * WED, 0, WED, HID, bv, EDIM, Vt, QKB, SEQ, 1.f, 4, 64);

  // Scores: S = Q K^T / 32   (M=N=S, K=E) -> grid (16 x 16 x 4) = 1024 blocks
  gemm256_kernel<2><<<dim3(16 * 16 * 4), 512, 131072, stream>>>(
      Qb, Kb, QKB, QKB, EDIM, nullptr, 0, Sb, SSB, SEQ, 0.03125f, 16, 256);

  // Softmax over rows, in place
  softmax_kernel<<<dim3(NHEAD * SEQ), 256, 0, stream>>>(Sb);

  // Out: O = P V  (M=S, N=E, K=S), written to out[s][head*E + e] as f32
  gemm256_kernel<3><<<dim3(4 * 16 * 4), 512, 131072, stream>>>(
      Sb, Vt, SSB, QKB, SEQ, nullptr, 0, out, (long long)EDIM, NHEAD * EDIM, 1.f, 4, 64);
}

// Round 3
// 717.032 us; speedup vs baseline: 1.7251x; 1.0725x over previous
//
#include <hip/hip_runtime.h>

#define SEQ   4096
#define HID   4096
#define EDIM  1024
#define NHEAD 4

typedef __attribute__((ext_vector_type(8))) short short8;
typedef __attribute__((ext_vector_type(4))) float f32x4;

typedef const __attribute__((address_space(1))) void* gas_ptr;
typedef __attribute__((address_space(3))) void* las_ptr;
#define GLD16(g, l) __builtin_amdgcn_global_load_lds((gas_ptr)(g), (las_ptr)(l), 16, 0, 0)

#define BARRIER() __builtin_amdgcn_s_barrier()
#define SCHED0()  __builtin_amdgcn_sched_barrier(0)

__device__ __forceinline__ unsigned short f2bf(float f) {
  union { float f; unsigned u; } v; v.f = f;
  unsigned r = v.u + 0x7fffu + ((v.u >> 16) & 1u);  // RNE
  return (unsigned short)(r >> 16);
}
__device__ __forceinline__ float bf2f(unsigned short u) {
  union { unsigned u; float f; } v; v.u = ((unsigned)u) << 16;
  return v.f;
}

// ---------------- h: f32 -> bf16 ----------------
__global__ __launch_bounds__(256) void hconv_kernel(const float* __restrict__ in,
                                                    unsigned short* __restrict__ out) {
  size_t i = ((size_t)blockIdx.x * 256 + threadIdx.x) * 8;
  const float4 a = *(const float4*)(in + i);
  const float4 b = *(const float4*)(in + i + 4);
  short8 o;
  o[0] = (short)f2bf(a.x); o[1] = (short)f2bf(a.y);
  o[2] = (short)f2bf(a.z); o[3] = (short)f2bf(a.w);
  o[4] = (short)f2bf(b.x); o[5] = (short)f2bf(b.y);
  o[6] = (short)f2bf(b.z); o[7] = (short)f2bf(b.w);
  *(short8*)(out + i) = o;
}

// ---------------- W [mat][head][D][E] f32 -> Wt [mat*4+head][E][D] bf16 ----------------
__global__ __launch_bounds__(256) void wconv_kernel(const float* __restrict__ Wq,
                                                    const float* __restrict__ Wk,
                                                    const float* __restrict__ Wv,
                                                    unsigned short* __restrict__ wt) {
  const int mh = blockIdx.y;               // 0..11
  const int mat = mh >> 2, head = mh & 3;
  const float* W = (mat == 0 ? Wq : (mat == 1 ? Wk : Wv)) + (size_t)head * HID * EDIM; // [D][E]
  unsigned short* out = wt + (size_t)mh * EDIM * HID;                                  // [E][D]
  const int tile = blockIdx.x;             // (D/64)*(E/64) = 64*16
  const int td = tile >> 4;                // d-tile 0..63
  const int te = tile & 15;                // e-tile 0..15
  __shared__ float lds[64][65];
  const int tid = threadIdx.x;
  const int r = tid >> 4, c4 = (tid & 15) * 4;
#pragma unroll
  for (int it = 0; it < 4; ++it) {
    int dr = r + 16 * it;
    const float4 v = *(const float4*)&W[(size_t)(td * 64 + dr) * EDIM + te * 64 + c4];
    lds[dr][c4 + 0] = v.x; lds[dr][c4 + 1] = v.y;
    lds[dr][c4 + 2] = v.z; lds[dr][c4 + 3] = v.w;
  }
  __syncthreads();
#pragma unroll
  for (int it = 0; it < 4; ++it) {
    int er = r + 16 * it;
    ushort4 o;
    o.x = f2bf(lds[c4 + 0][er]); o.y = f2bf(lds[c4 + 1][er]);
    o.z = f2bf(lds[c4 + 2][er]); o.w = f2bf(lds[c4 + 3][er]);
    *(ushort4*)&out[(size_t)(te * 64 + er) * HID + td * 64 + c4] = o;
  }
}

// ---------------- 256x256 8-phase bf16 MFMA GEMM, C = A * Bt^T ----------------
// m201-faithful port: BK=64, 8 waves (2Mx4N, 128x64/wave), 2-slot LDS double buffer
// (64KB/tile: A 32KB + B 32KB, each 2 halves of 128x64), 8 phases per 2 K-tiles.
// Per-tile phases: ph1 reads {av[m0-3],bv[n0-1]} (12 b128), ph2 {bv[n2-3]} (4),
// ph3 {av[m4-7]} (8), ph4 none (pure MFMA). Stages (2 x global_load_lds / phase):
// ph1:A0(t+1) ph2:A1(t+1) ph3:B0(t+2) ph4:B1(t+2) ph5:A0(t+2) ph6:A1(t+2)
// ph7:B0(t+3) ph8:B1(t+3). Region-death: B-halves die after ph2/ph6 end-barrier,
// A-halves after ph3/ph7 -> every stage targets a dead region. Counted vmcnt(4) at
// ph4/ph8 (never 0 in steady state); vmcnt(0) fallback when tail stages guarded out.
// XOR swizzle: phys 16B-slot = logical k-slot ^ (row&7); staging source pre-permuted.
// MODE 0: bf16 out [row][col], +bias[col]
// MODE 1: bf16 out [col][row], +bias[col]   (transposed write, for V^T)
// MODE 2: bf16 out [row][col], *scale       (scores)
// MODE 3: f32  out [row][col]               (final output)
template <int MODE>
__global__ __launch_bounds__(512, 2) void gemm256_kernel(
    const unsigned short* __restrict__ Aall, const unsigned short* __restrict__ Ball,
    long long aBatch, long long bBatch, int K,
    const float* __restrict__ biasAll, long long biasBatch,
    void* __restrict__ outAll, long long outBatch, int ldOut, float scale,
    int gx, int gxy) {
  extern __shared__ char smem[];

  // XCD-aware bijective block swizzle (all grids have nwg % 8 == 0)
  const int nwg = (int)gridDim.x;
  const int lin = (int)blockIdx.x;
  int wg = (lin & 7) * (nwg >> 3) + (lin >> 3);
  const int z = wg / gxy; wg -= z * gxy;
  const int by = wg / gx;
  const int bx = wg - by * gx;
  const int bm = by * 256, bn = bx * 256;

  const unsigned short* A = Aall + (size_t)z * aBatch;
  const unsigned short* B = Ball + (size_t)z * bBatch;

  const int tid = threadIdx.x;           // 0..511
  const int lane = tid & 63, wid = tid >> 6;
  const int wr = wid >> 2, wc = wid & 3; // wave -> (2 x 4) output grid
  const int li = lane & 15, lg = lane >> 4;

  // ---- staging addresses: half-tile = 128 rows x 64 k = 1024 16B chunks.
  // thread covers chunks tid (j=0, rows 0..63) and tid+512 (j=1, rows 64..127).
  // chunk: row = c>>3, phys slot = c&7, logical k-slot = phys ^ (row&7).
  const int srow = tid >> 3;                               // 0..63
  const int sk = ((tid & 7) ^ (srow & 7)) * 8;             // same for j=0/1 (64%8==0)
  const unsigned short* aS00 = A + (size_t)(bm +   0 + srow) * K + sk;
  const unsigned short* aS01 = A + (size_t)(bm +  64 + srow) * K + sk;
  const unsigned short* aS10 = A + (size_t)(bm + 128 + srow) * K + sk;
  const unsigned short* aS11 = A + (size_t)(bm + 192 + srow) * K + sk;
  const unsigned short* bS00 = B + (size_t)(bn +   0 + srow) * K + sk;
  const unsigned short* bS01 = B + (size_t)(bn +  64 + srow) * K + sk;
  const unsigned short* bS10 = B + (size_t)(bn + 128 + srow) * K + sk;
  const unsigned short* bS11 = B + (size_t)(bn + 192 + srow) * K + sk;

// regionOff: A half0=0, A half1=16384, B half0=32768, B half1=49152
#define STG(p0, p1, regionOff, tt)                                        \
  do {                                                                    \
    char* _d = smem + (((tt) & 1) << 16) + (regionOff) + tid * 16;        \
    GLD16((p0) + (size_t)(tt) * 64, _d);                                  \
    GLD16((p1) + (size_t)(tt) * 64, _d + 8192);                           \
  } while (0)

  // ---- swizzled ds_read bases: row stride 128B, slot = (ks*4+lg) ^ (li&7)
  const int aBase = (wr * 128 + li) * 128;
  const int bBase = 32768 + (wc * 64 + li) * 128;
  const int axk0 = ((0 + lg) ^ (li & 7)) * 16;   // ks=0
  const int axk1 = ((4 + lg) ^ (li & 7)) * 16;   // ks=1

  f32x4 acc[8][4];
#pragma unroll
  for (int m = 0; m < 8; ++m)
#pragma unroll
    for (int n = 0; n < 4; ++n) acc[m][n] = (f32x4){0.f, 0.f, 0.f, 0.f};

  const int NT = K >> 6;    // K-tiles of 64
  const int NI = NT >> 1;

  // ---- prologue: A(0), B(0), B(1)  (12 loads); wait tile0's 8 landed
  STG(aS00, aS01, 0, 0);
  STG(aS10, aS11, 16384, 0);
  STG(bS00, bS01, 32768, 0);
  STG(bS10, bS11, 49152, 0);
  STG(bS00, bS01, 32768, 1);
  STG(bS10, bS11, 49152, 1);
  asm volatile("s_waitcnt vmcnt(4)" ::: "memory");
  BARRIER();
  SCHED0();

  short8 av[4][2], bv[4][2];

  for (int i = 0; i < NI; ++i) {
    const int t = 2 * i;
    const char* s0 = smem;            // even tile slot
    const char* s1 = smem + 65536;    // odd tile slot

    // ============ ph1: tile t, (m0-3 x n0-1) ============
#pragma unroll
    for (int m = 0; m < 4; ++m) {
      av[m][0] = *(const short8*)(s0 + aBase + m * 2048 + axk0);
      av[m][1] = *(const short8*)(s0 + aBase + m * 2048 + axk1);
    }
#pragma unroll
    for (int n = 0; n < 2; ++n) {
      bv[n][0] = *(const short8*)(s0 + bBase + n * 2048 + axk0);
      bv[n][1] = *(const short8*)(s0 + bBase + n * 2048 + axk1);
    }
    STG(aS00, aS01, 0, t + 1);
    asm volatile("s_waitcnt lgkmcnt(8)" ::: "memory");
    SCHED0();
    BARRIER();
    asm volatile("s_waitcnt lgkmcnt(0)" ::: "memory");
    SCHED0();
    __builtin_amdgcn_s_setprio(1);
#pragma unroll
    for (int m = 0; m < 4; ++m)
#pragma unroll
      for (int n = 0; n < 2; ++n) {
        acc[m][n] = __builtin_amdgcn_mfma_f32_16x16x32_bf16(av[m][0], bv[n][0], acc[m][n], 0, 0, 0);
        acc[m][n] = __builtin_amdgcn_mfma_f32_16x16x32_bf16(av[m][1], bv[n][1], acc[m][n], 0, 0, 0);
      }
    __builtin_amdgcn_s_setprio(0);
    SCHED0();
    BARRIER();

    // ============ ph2: tile t, (m0-3 x n2-3) ============
#pragma unroll
    for (int n = 2; n < 4; ++n) {
      bv[n][0] = *(const short8*)(s0 + bBase + n * 2048 + axk0);
      bv[n][1] = *(const short8*)(s0 + bBase + n * 2048 + axk1);
    }
    STG(aS10, aS11, 16384, t + 1);
    SCHED0();
    BARRIER();
    asm volatile("s_waitcnt lgkmcnt(0)" ::: "memory");
    SCHED0();
    __builtin_amdgcn_s_setprio(1);
#pragma unroll
    for (int m = 0; m < 4; ++m)
#pragma unroll
      for (int n = 2; n < 4; ++n) {
        acc[m][n] = __builtin_amdgcn_mfma_f32_16x16x32_bf16(av[m][0], bv[n][0], acc[m][n], 0, 0, 0);
        acc[m][n] = __builtin_amdgcn_mfma_f32_16x16x32_bf16(av[m][1], bv[n][1], acc[m][n], 0, 0, 0);
      }
    __builtin_amdgcn_s_setprio(0);
    SCHED0();
    BARRIER();

    // ============ ph3: tile t, (m4-7 x n0-1) ============
#pragma unroll
    for (int m = 0; m < 4; ++m) {
      av[m][0] = *(const short8*)(s0 + aBase + (m + 4) * 2048 + axk0);
      av[m][1] = *(const short8*)(s0 + aBase + (m + 4) * 2048 + axk1);
    }
    if (t + 2 < NT) STG(bS00, bS01, 32768, t + 2);
    SCHED0();
    BARRIER();
    asm volatile("s_waitcnt lgkmcnt(0)" ::: "memory");
    SCHED0();
    __builtin_amdgcn_s_setprio(1);
#pragma unroll
    for (int m = 0; m < 4; ++m)
#pragma unroll
      for (int n = 0; n < 2; ++n) {
        acc[m + 4][n] = __builtin_amdgcn_mfma_f32_16x16x32_bf16(av[m][0], bv[n][0], acc[m + 4][n], 0, 0, 0);
        acc[m + 4][n] = __builtin_amdgcn_mfma_f32_16x16x32_bf16(av[m][1], bv[n][1], acc[m + 4][n], 0, 0, 0);
      }
    __builtin_amdgcn_s_setprio(0);
    SCHED0();
    BARRIER();

    // ============ ph4: tile t, (m4-7 x n2-3), no ds reads ============
    if (t + 2 < NT) {
      STG(bS10, bS11, 49152, t + 2);
      asm volatile("s_waitcnt vmcnt(4)" ::: "memory");
    } else {
      asm volatile("s_waitcnt vmcnt(0)" ::: "memory");
    }
    SCHED0();
    BARRIER();
    __builtin_amdgcn_s_setprio(1);
#pragma unroll
    for (int m = 0; m < 4; ++m)
#pragma unroll
      for (int n = 2; n < 4; ++n) {
        acc[m + 4][n] = __builtin_amdgcn_mfma_f32_16x16x32_bf16(av[m][0], bv[n][0], acc[m + 4][n], 0, 0, 0);
        acc[m + 4][n] = __builtin_amdgcn_mfma_f32_16x16x32_bf16(av[m][1], bv[n][1], acc[m + 4][n], 0, 0, 0);
      }
    __builtin_amdgcn_s_setprio(0);
    SCHED0();
    BARRIER();

    // ============ ph5: tile t+1, (m0-3 x n0-1) ============
#pragma unroll
    for (int m = 0; m < 4; ++m) {
      av[m][0] = *(const short8*)(s1 + aBase + m * 2048 + axk0);
      av[m][1] = *(const short8*)(s1 + aBase + m * 2048 + axk1);
    }
#pragma unroll
    for (int n = 0; n < 2; ++n) {
      bv[n][0] = *(const short8*)(s1 + bBase + n * 2048 + axk0);
      bv[n][1] = *(const short8*)(s1 + bBase + n * 2048 + axk1);
    }
    if (t + 2 < NT) STG(aS00, aS01, 0, t + 2);
    asm volatile("s_waitcnt lgkmcnt(8)" ::: "memory");
    SCHED0();
    BARRIER();
    asm volatile("s_waitcnt lgkmcnt(0)" ::: "memory");
    SCHED0();
    __builtin_amdgcn_s_setprio(1);
#pragma unroll
    for (int m = 0; m < 4; ++m)
#pragma unroll
      for (int n = 0; n < 2; ++n) {
        acc[m][n] = __builtin_amdgcn_mfma_f32_16x16x32_bf16(av[m][0], bv[n][0], acc[m][n], 0, 0, 0);
        acc[m][n] = __builtin_amdgcn_mfma_f32_16x16x32_bf16(av[m][1], bv[n][1], acc[m][n], 0, 0, 0);
      }
    __builtin_amdgcn_s_setprio(0);
    SCHED0();
    BARRIER();

    // ============ ph6: tile t+1, (m0-3 x n2-3) ============
#pragma unroll
    for (int n = 2; n < 4; ++n) {
      bv[n][0] = *(const short8*)(s1 + bBase + n * 2048 + axk0);
      bv[n][1] = *(const short8*)(s1 + bBase + n * 2048 + axk1);
    }
    if (t + 2 < NT) STG(aS10, aS11, 16384, t + 2);
    SCHED0();
    BARRIER();
    asm volatile("s_waitcnt lgkmcnt(0)" ::: "memory");
    SCHED0();
    __builtin_amdgcn_s_setprio(1);
#pragma unroll
    for (int m = 0; m < 4; ++m)
#pragma unroll
      for (int n = 2; n < 4; ++n) {
        acc[m][n] = __builtin_amdgcn_mfma_f32_16x16x32_bf16(av[m][0], bv[n][0], acc[m][n], 0, 0, 0);
        acc[m][n] = __builtin_amdgcn_mfma_f32_16x16x32_bf16(av[m][1], bv[n][1], acc[m][n], 0, 0, 0);
      }
    __builtin_amdgcn_s_setprio(0);
    SCHED0();
    BARRIER();

    // ============ ph7: tile t+1, (m4-7 x n0-1) ============
#pragma unroll
    for (int m = 0; m < 4; ++m) {
      av[m][0] = *(const short8*)(s1 + aBase + (m + 4) * 2048 + axk0);
      av[m][1] = *(const short8*)(s1 + aBase + (m + 4) * 2048 + axk1);
    }
    if (t + 3 < NT) STG(bS00, bS01, 32768, t + 3);
    SCHED0();
    BARRIER();
    asm volatile("s_waitcnt lgkmcnt(0)" ::: "memory");
    SCHED0();
    __builtin_amdgcn_s_setprio(1);
#pragma unroll
    for (int m = 0; m < 4; ++m)
#pragma unroll
      for (int n = 0; n < 2; ++n) {
        acc[m + 4][n] = __builtin_amdgcn_mfma_f32_16x16x32_bf16(av[m][0], bv[n][0], acc[m + 4][n], 0, 0, 0);
        acc[m + 4][n] = __builtin_amdgcn_mfma_f32_16x16x32_bf16(av[m][1], bv[n][1], acc[m + 4][n], 0, 0, 0);
      }
    __builtin_amdgcn_s_setprio(0);
    SCHED0();
    BARRIER();

    // ============ ph8: tile t+1, (m4-7 x n2-3), no ds reads ============
    if (t + 3 < NT) {
      STG(bS10, bS11, 49152, t + 3);
      asm volatile("s_waitcnt vmcnt(4)" ::: "memory");
    } else {
      asm volatile("s_waitcnt vmcnt(0)" ::: "memory");
    }
    SCHED0();
    BARRIER();
    __builtin_amdgcn_s_setprio(1);
#pragma unroll
    for (int m = 0; m < 4; ++m)
#pragma unroll
      for (int n = 2; n < 4; ++n) {
        acc[m + 4][n] = __builtin_amdgcn_mfma_f32_16x16x32_bf16(av[m][0], bv[n][0], acc[m + 4][n], 0, 0, 0);
        acc[m + 4][n] = __builtin_amdgcn_mfma_f32_16x16x32_bf16(av[m][1], bv[n][1], acc[m + 4][n], 0, 0, 0);
      }
    __builtin_amdgcn_s_setprio(0);
    SCHED0();
    BARRIER();
  }
#undef STG

  // ---- epilogue
  float bvv[4];
  if (MODE == 0 || MODE == 1) {
    const float* bias = biasAll + (size_t)z * biasBatch;
#pragma unroll
    for (int n = 0; n < 4; ++n) bvv[n] = bias[bn + wc * 64 + n * 16 + li];
  }
#pragma unroll
  for (int m = 0; m < 8; ++m)
#pragma unroll
    for (int n = 0; n < 4; ++n)
#pragma unroll
      for (int r = 0; r < 4; ++r) {
        const int grow = bm + wr * 128 + m * 16 + lg * 4 + r;
        const int gcol = bn + wc * 64 + n * 16 + li;
        float val = acc[m][n][r];
        if (MODE == 0 || MODE == 1) val += bvv[n];
        if (MODE == 2) val *= scale;
        if (MODE == 0 || MODE == 2) {
          unsigned short* o = (unsigned short*)outAll + (size_t)z * outBatch;
          o[(size_t)grow * ldOut + gcol] = f2bf(val);
        } else if (MODE == 1) {
          unsigned short* o = (unsigned short*)outAll + (size_t)z * outBatch;
          o[(size_t)gcol * ldOut + grow] = f2bf(val);
        } else {
          float* o = (float*)outAll + (size_t)z * outBatch;
          o[(size_t)grow * ldOut + gcol] = val;
        }
      }
}

// ---------------- row softmax, in place on bf16 [nrows][SEQ] ----------------
__global__ __launch_bounds__(256) void softmax_kernel(unsigned short* __restrict__ Sb) {
  const size_t row = blockIdx.x;
  unsigned short* p = Sb + row * (size_t)SEQ;
  const int tid = threadIdx.x;
  const int lane = tid & 63, wid = tid >> 6;
  float v[16];
  const short8 u0 = *(const short8*)&p[tid * 16];
  const short8 u1 = *(const short8*)&p[tid * 16 + 8];
#pragma unroll
  for (int j = 0; j < 8; ++j) v[j] = bf2f((unsigned short)u0[j]);
#pragma unroll
  for (int j = 0; j < 8; ++j) v[8 + j] = bf2f((unsigned short)u1[j]);
  float mx = v[0];
#pragma unroll
  for (int j = 1; j < 16; ++j) mx = fmaxf(mx, v[j]);
#pragma unroll
  for (int off = 32; off; off >>= 1) mx = fmaxf(mx, __shfl_xor(mx, off));
  __shared__ float red[8];
  if (lane == 0) red[wid] = mx;
  __syncthreads();
  mx = fmaxf(fmaxf(red[0], red[1]), fmaxf(red[2], red[3]));
  float s = 0.f;
#pragma unroll
  for (int j = 0; j < 16; ++j) { v[j] = __expf(v[j] - mx); s += v[j]; }
#pragma unroll
  for (int off = 32; off; off >>= 1) s += __shfl_xor(s, off);
  if (lane == 0) red[4 + wid] = s;
  __syncthreads();
  s = (red[4] + red[5]) + (red[6] + red[7]);
  const float inv = 1.0f / s;
  short8 o0, o1;
#pragma unroll
  for (int j = 0; j < 8; ++j) o0[j] = (short)f2bf(v[j] * inv);
#pragma unroll
  for (int j = 0; j < 8; ++j) o1[j] = (short)f2bf(v[8 + j] * inv);
  *(short8*)&p[tid * 16] = o0;
  *(short8*)&p[tid * 16 + 8] = o1;
}

extern "C" void kernel_launch(void* const* d_in, const int* in_sizes, int n_in,
                              void* d_out, int out_size, void* d_ws, size_t ws_size,
                              hipStream_t stream) {
  const float* h  = (const float*)d_in[0];
  const float* Wq = (const float*)d_in[1];
  const float* bq = (const float*)d_in[2];
  const float* Wk = (const float*)d_in[3];
  const float* bk = (const float*)d_in[4];
  const float* Wv = (const float*)d_in[5];
  const float* bv = (const float*)d_in[6];
  float* out = (float*)d_out;
  char* ws = (char*)d_ws;

  // allow 128KB dynamic LDS for the GEMM kernels (idempotent, not a stream op)
  (void)hipFuncSetAttribute((const void*)&gemm256_kernel<0>,
                            hipFuncAttributeMaxDynamicSharedMemorySize, 131072);
  (void)hipFuncSetAttribute((const void*)&gemm256_kernel<1>,
                            hipFuncAttributeMaxDynamicSharedMemorySize, 131072);
  (void)hipFuncSetAttribute((const void*)&gemm256_kernel<2>,
                            hipFuncAttributeMaxDynamicSharedMemorySize, 131072);
  (void)hipFuncSetAttribute((const void*)&gemm256_kernel<3>,
                            hipFuncAttributeMaxDynamicSharedMemorySize, 131072);

  // ws layout (224 MB):
  //  [0,32MB)    h_bf16 [S][HID]          -- dead after projections
  //  [32,128MB)  Wt bf16 [12][E][HID]     -- dead after projections
  //  [0,128MB)   Sb bf16 [H][S][S]        -- scores/probs (reuses the two above)
  //  [128,160)   Qb bf16 [H][S][E]
  //  [160,192)   Kb bf16 [H][S][E]
  //  [192,224)   Vt bf16 [H][E][S]
  unsigned short* hB = (unsigned short*)ws;
  unsigned short* wt = (unsigned short*)(ws + (32ull << 20));
  unsigned short* Sb = (unsigned short*)ws;
  unsigned short* Qb = (unsigned short*)(ws + (128ull << 20));
  unsigned short* Kb = (unsigned short*)(ws + (160ull << 20));
  unsigned short* Vt = (unsigned short*)(ws + (192ull << 20));

  const long long WED = (long long)EDIM * HID;   // per-(mat,head) Wt elems
  const long long QKB = (long long)SEQ * EDIM;   // per-head Q/K elems
  const long long SSB = (long long)SEQ * SEQ;    // per-head score elems

  hconv_kernel<<<dim3((SEQ * (size_t)HID) / (256 * 8)), 256, 0, stream>>>(h, hB);
  wconv_kernel<<<dim3((HID / 64) * (EDIM / 64), 12), 256, 0, stream>>>(Wq, Wk, Wv, wt);

  // Projections: M=S=4096, N=E=1024, K=HID  -> grid (4 x 16 x 4) = 256 blocks, 1-D
  gemm256_kernel<0><<<dim3(4 * 16 * 4), 512, 131072, stream>>>(
      hB, wt + 0 * WED, 0, WED, HID, bq, EDIM, Qb, QKB, EDIM, 1.f, 4, 64);
  gemm256_kernel<0><<<dim3(4 * 16 * 4), 512, 131072, stream>>>(
      hB, wt + 4 * WED, 0, WED, HID, bk, EDIM, Kb, QKB, EDIM, 1.f, 4, 64);
  gemm256_kernel<1><<<dim3(4 * 16 * 4), 512, 131072, stream>>>(
      hB, wt + 8 * WED, 0, WED, HID, bv, EDIM, Vt, QKB, SEQ, 1.f, 4, 64);

  // Scores: S = Q K^T / 32   (M=N=S, K=E) -> grid (16 x 16 x 4) = 1024 blocks
  gemm256_kernel<2><<<dim3(16 * 16 * 4), 512, 131072, stream>>>(
      Qb, Kb, QKB, QKB, EDIM, nullptr, 0, Sb, SSB, SEQ, 0.03125f, 16, 256);

  // Softmax over rows, in place
  softmax_kernel<<<dim3(NHEAD * SEQ), 256, 0, stream>>>(Sb);

  // Out: O = P V  (M=S, N=E, K=S), written to out[s][head*E + e] as f32
  gemm256_kernel<3><<<dim3(4 * 16 * 4), 512, 131072, stream>>>(
      Sb, Vt, SSB, QKB, SEQ, nullptr, 0, out, (long long)EDIM, NHEAD * EDIM, 1.f, 4, 64);
}